// Round 2
// baseline (746.401 us; speedup 1.0000x reference)
//
#include <hip/hip_runtime.h>
#include <hip/hip_bf16.h>

typedef __hip_bfloat16 bf16;
typedef __attribute__((ext_vector_type(8))) short bf16x8;
typedef __attribute__((ext_vector_type(4))) float f32x4;

#define SEQ     2048
#define DMODEL  1024
#define DINNER  2048
#define NBATCH  4
#define NROWS   (NBATCH * SEQ)   // 8192
#define DSTATE  16
#define NCHUNK  16
#define CHUNK   128              // SEQ / NCHUNK

__device__ __forceinline__ float b2f(short s) {
    union { unsigned u; float f; } c;
    c.u = ((unsigned)(unsigned short)s) << 16;
    return c.f;
}

// ---------------------------------------------------------------------------
// Transpose + cast fp32 (K x N) -> bf16 (Npad x K), zero-filling rows >= N.
// ---------------------------------------------------------------------------
__global__ __launch_bounds__(256)
void transpose_cast(const float* __restrict__ W, bf16* __restrict__ WT,
                    int K, int N, int Npad)
{
    __shared__ float tile[32][33];
    const int bx = blockIdx.x;            // along N (padded)
    const int by = blockIdx.y;            // along K
    const int tx = threadIdx.x, ty = threadIdx.y;
    const int x = bx * 32 + tx;           // N index
#pragma unroll
    for (int i = 0; i < 32; i += 8) {
        int y = by * 32 + ty + i;         // K index
        tile[ty + i][tx] = (x < N && y < K) ? W[(size_t)y * N + x] : 0.f;
    }
    __syncthreads();
    const int k = by * 32 + tx;
#pragma unroll
    for (int i = 0; i < 32; i += 8) {
        int n = bx * 32 + ty + i;
        if (n < Npad && k < K)
            WT[(size_t)n * K + k] = __float2bfloat16(tile[tx][ty + i]);
    }
}

// ---------------------------------------------------------------------------
// Elementwise fp32 -> bf16 cast
// ---------------------------------------------------------------------------
__global__ __launch_bounds__(256)
void cast_to_bf16(const float* __restrict__ in, bf16* __restrict__ out, int n4)
{
    int i = blockIdx.x * 256 + threadIdx.x;
    if (i < n4) {
        float4 v = *(const float4*)(in + (size_t)i * 4);
        __align__(8) bf16 o[4] = { __float2bfloat16(v.x), __float2bfloat16(v.y),
                                   __float2bfloat16(v.z), __float2bfloat16(v.w) };
        *(uint2*)(out + (size_t)i * 4) = *(uint2*)o;
    }
}

// ---------------------------------------------------------------------------
// GEMM: C[M,N] = A[M,K] @ B^T[N,K]   (bf16 in, fp32 accum). A row stride lda,
// BT compact (stride K), C row stride ldc.
// MODE 0: store fp32. MODE 1: bf16 softplus(acc+bias[col]). MODE 2: bf16.
// 128x128 tile, BK=32, 256 threads (4 waves, 64x64 each, 4x4 MFMA tiles)
// ---------------------------------------------------------------------------
template <int MODE>
__global__ __launch_bounds__(256, 2)
void gemm_bt(const bf16* __restrict__ A, int lda, const bf16* __restrict__ BT,
             float* __restrict__ Cf, bf16* __restrict__ Cb, int ldc,
             const float* __restrict__ bias, int M, int N, int K)
{
    __shared__ __align__(16) bf16 As[128 * 32];
    __shared__ __align__(16) bf16 Bs[128 * 32];
    const int tid  = threadIdx.x;
    const int lane = tid & 63;
    const int wave = tid >> 6;
    const int m0 = blockIdx.y * 128;
    const int n0 = blockIdx.x * 128;
    const int wm = (wave & 1) * 64;
    const int wn = (wave >> 1) * 64;

    f32x4 acc[4][4];
#pragma unroll
    for (int i = 0; i < 4; ++i)
#pragma unroll
        for (int j = 0; j < 4; ++j) acc[i][j] = (f32x4){0.f, 0.f, 0.f, 0.f};

    // staging: 512 16B-chunks per tile, 2 per thread
    const int c0 = tid, c1 = tid + 256;
    const int ar0 = c0 >> 2, ac0 = (c0 & 3) * 8;
    const int ar1 = c1 >> 2, ac1 = (c1 & 3) * 8;
    const bf16* pa0 = A  + (size_t)(m0 + ar0) * lda + ac0;
    const bf16* pa1 = A  + (size_t)(m0 + ar1) * lda + ac1;
    const bf16* pb0 = BT + (size_t)(n0 + ar0) * K + ac0;
    const bf16* pb1 = BT + (size_t)(n0 + ar1) * K + ac1;

    bf16x8 va0 = *(const bf16x8*)pa0;
    bf16x8 va1 = *(const bf16x8*)pa1;
    bf16x8 vb0 = *(const bf16x8*)pb0;
    bf16x8 vb1 = *(const bf16x8*)pb1;

    const int arow = lane & 15;
    const int akq  = (lane >> 4) * 8;
    const int KT = K >> 5;

    for (int kt = 0; kt < KT; ++kt) {
        __syncthreads();   // previous iteration's LDS reads done
        *(bf16x8*)(As + c0 * 8) = va0;
        *(bf16x8*)(As + c1 * 8) = va1;
        *(bf16x8*)(Bs + c0 * 8) = vb0;
        *(bf16x8*)(Bs + c1 * 8) = vb1;
        __syncthreads();
        if (kt + 1 < KT) {          // register prefetch of next tile
            int k0 = (kt + 1) * 32;
            va0 = *(const bf16x8*)(pa0 + k0);
            va1 = *(const bf16x8*)(pa1 + k0);
            vb0 = *(const bf16x8*)(pb0 + k0);
            vb1 = *(const bf16x8*)(pb1 + k0);
        }
        bf16x8 af[4], bfr[4];
#pragma unroll
        for (int i = 0; i < 4; ++i)
            af[i] = *(const bf16x8*)(As + (wm + i * 16 + arow) * 32 + akq);
#pragma unroll
        for (int j = 0; j < 4; ++j)
            bfr[j] = *(const bf16x8*)(Bs + (wn + j * 16 + arow) * 32 + akq);
#pragma unroll
        for (int i = 0; i < 4; ++i)
#pragma unroll
            for (int j = 0; j < 4; ++j)
                acc[i][j] = __builtin_amdgcn_mfma_f32_16x16x32_bf16(
                    af[i], bfr[j], acc[i][j], 0, 0, 0);
    }

    // epilogue: C/D layout col = lane&15, row = (lane>>4)*4 + reg
    const int rbase = (lane >> 4) * 4;
    const int cbase = lane & 15;
#pragma unroll
    for (int i = 0; i < 4; ++i) {
        int row = m0 + wm + i * 16 + rbase;
#pragma unroll
        for (int j = 0; j < 4; ++j) {
            int col = n0 + wn + j * 16 + cbase;
#pragma unroll
            for (int r = 0; r < 4; ++r) {
                float v = acc[i][j][r];
                size_t idx = (size_t)(row + r) * ldc + col;
                if (MODE == 0) {
                    Cf[idx] = v;
                } else if (MODE == 1) {
                    v += bias[col];
                    float sp = (v > 20.f) ? v : log1pf(__expf(v));
                    Cb[idx] = __float2bfloat16(sp);
                } else {
                    Cb[idx] = __float2bfloat16(v);
                }
            }
        }
    }
}

// ---------------------------------------------------------------------------
// Causal depthwise conv (d_conv=4) + bias + SiLU. Reads bf16 x_inner =
// xz[:, :2048] (row stride 4096). One thread per (row, 8 channels).
// ---------------------------------------------------------------------------
__global__ __launch_bounds__(256)
void conv_silu(const bf16* __restrict__ xz, const float* __restrict__ conv_w,
               const float* __restrict__ conv_b, bf16* __restrict__ xc)
{
    int gid = blockIdx.x * 256 + threadIdx.x;   // NROWS * 256
    int d8  = gid & 255;
    int row = gid >> 8;
    int l   = row & (SEQ - 1);
    int d   = d8 * 8;
    const bf16* base = xz + (size_t)row * 4096 + d;
    float acc[8];
    float4 b0 = *(const float4*)(conv_b + d);
    float4 b1 = *(const float4*)(conv_b + d + 4);
    acc[0] = b0.x; acc[1] = b0.y; acc[2] = b0.z; acc[3] = b0.w;
    acc[4] = b1.x; acc[5] = b1.y; acc[6] = b1.z; acc[7] = b1.w;
    float w[8][4];
#pragma unroll
    for (int j = 0; j < 8; ++j) {
        float4 wv = *(const float4*)(conv_w + (size_t)(d + j) * 4);
        w[j][0] = wv.x; w[j][1] = wv.y; w[j][2] = wv.z; w[j][3] = wv.w;
    }
#pragma unroll
    for (int k = 0; k < 4; ++k) {
        if (l + k - 3 >= 0) {   // wave-uniform branch (row is block-uniform)
            bf16x8 v = *(const bf16x8*)(base + (ptrdiff_t)(k - 3) * 4096);
#pragma unroll
            for (int j = 0; j < 8; ++j)
                acc[j] = fmaf(b2f(v[j]), w[j][k], acc[j]);
        }
    }
    __align__(16) bf16 o[8];
#pragma unroll
    for (int j = 0; j < 8; ++j) {
        float s = acc[j] / (1.f + __expf(-acc[j]));
        o[j] = __float2bfloat16(s);
    }
    *(bf16x8*)(xc + (size_t)row * DINNER + d) = *(bf16x8*)o;
}

// ---------------------------------------------------------------------------
// Chunked selective scan, pass 1: per (b, chunk, d): P = prod(a_t), S = local h
// layout P/S[c][b][d][n]
// ---------------------------------------------------------------------------
__global__ __launch_bounds__(256)
void scan_pass1(const bf16* __restrict__ xc, const bf16* __restrict__ dt,
                const float* __restrict__ bdt, const float* __restrict__ A_log,
                float* __restrict__ P, float* __restrict__ S)
{
    const int d  = blockIdx.x * 256 + threadIdx.x;
    const int c  = blockIdx.y;
    const int b  = blockIdx.z;
    const int t0 = c * CHUNK;
    __shared__ float bls[CHUNK][DSTATE];
    for (int i = threadIdx.x; i < CHUNK * DSTATE; i += 256) {
        int tl = i >> 4, col = i & 15;
        bls[tl][col] = bdt[(size_t)(b * SEQ + t0 + tl) * 128 + col];
    }
    __syncthreads();
    float acoef[16], h[16], p[16];
#pragma unroll
    for (int n = 0; n < 16; ++n) {
        acoef[n] = -__expf(A_log[(size_t)d * 16 + n]) * 1.44269504f;
        h[n] = 0.f; p[n] = 1.f;
    }
    size_t idx = (size_t)(b * SEQ + t0) * DINNER + d;
    for (int tl = 0; tl < CHUNK; ++tl, idx += DINNER) {
        float dtv = __bfloat162float(dt[idx]);
        float xv  = __bfloat162float(xc[idx]);
        float u = dtv * xv;
#pragma unroll
        for (int n = 0; n < 16; ++n) {
            float a = exp2f(dtv * acoef[n]);
            p[n] *= a;
            h[n] = fmaf(a, h[n], u * bls[tl][n]);
        }
    }
    size_t o = ((size_t)(c * NBATCH + b) * DINNER + d) * 16;
#pragma unroll
    for (int n = 0; n < 16; n += 4) {
        *(float4*)(P + o + n) = make_float4(p[n], p[n+1], p[n+2], p[n+3]);
        *(float4*)(S + o + n) = make_float4(h[n], h[n+1], h[n+2], h[n+3]);
    }
}

// ---------------------------------------------------------------------------
// Pass 2: sequential combine over chunks. One thread per (b,d,n).
// Hinit may alias P (each element read before overwrite, one owner thread).
// ---------------------------------------------------------------------------
__global__ __launch_bounds__(256)
void scan_pass2(const float* __restrict__ P, const float* __restrict__ S,
                float* __restrict__ Hinit)
{
    size_t idx = (size_t)blockIdx.x * 256 + threadIdx.x;
    const size_t stride = (size_t)NBATCH * DINNER * 16;
    float h = 0.f;
    for (int c = 0; c < NCHUNK; ++c) {
        size_t o = (size_t)c * stride + idx;
        float p = P[o];
        float s = S[o];
        Hinit[o] = h;
        h = fmaf(p, h, s);
    }
}

// ---------------------------------------------------------------------------
// Pass 3: replay chunk from true h_init; fuse y = scan + xc*D, * silu(z),
// cast bf16 into U (row stride 4096; reads z from cols 2048.. of same buffer)
// ---------------------------------------------------------------------------
__global__ __launch_bounds__(256)
void scan_pass3(const bf16* __restrict__ xc, const bf16* __restrict__ dt,
                const float* __restrict__ bdt, const float* __restrict__ A_log,
                const float* __restrict__ Hinit, const bf16* __restrict__ xzb,
                const float* __restrict__ Dp, bf16* __restrict__ U)
{
    const int d  = blockIdx.x * 256 + threadIdx.x;
    const int c  = blockIdx.y;
    const int b  = blockIdx.z;
    const int t0 = c * CHUNK;
    __shared__ float bls[CHUNK][DSTATE];
    __shared__ float cls[CHUNK][DSTATE];
    for (int i = threadIdx.x; i < CHUNK * 32; i += 256) {
        int tl = i >> 5, col = i & 31;
        float v = bdt[(size_t)(b * SEQ + t0 + tl) * 128 + col];
        if (col < 16) bls[tl][col] = v; else cls[tl][col - 16] = v;
    }
    __syncthreads();
    float acoef[16], h[16];
#pragma unroll
    for (int n = 0; n < 16; ++n)
        acoef[n] = -__expf(A_log[(size_t)d * 16 + n]) * 1.44269504f;
    size_t ho = ((size_t)(c * NBATCH + b) * DINNER + d) * 16;
#pragma unroll
    for (int n = 0; n < 16; n += 4) {
        float4 hv = *(const float4*)(Hinit + ho + n);
        h[n] = hv.x; h[n+1] = hv.y; h[n+2] = hv.z; h[n+3] = hv.w;
    }
    const float Dv = Dp[d];
    size_t idx  = (size_t)(b * SEQ + t0) * DINNER + d;
    size_t widx = (size_t)(b * SEQ + t0) * 4096 + d;   // U col d / z col 2048+d
    for (int tl = 0; tl < CHUNK; ++tl, idx += DINNER, widx += 4096) {
        float dtv = __bfloat162float(dt[idx]);
        float xv  = __bfloat162float(xc[idx]);
        float u = dtv * xv;
        float y = 0.f;
#pragma unroll
        for (int n = 0; n < 16; ++n) {
            float a = exp2f(dtv * acoef[n]);
            h[n] = fmaf(a, h[n], u * bls[tl][n]);
            y = fmaf(h[n], cls[tl][n], y);
        }
        float zv = __bfloat162float(xzb[widx + DINNER]);
        float sz = zv / (1.f + __expf(-zv));
        float val = (y + xv * Dv) * sz;
        U[widx] = __float2bfloat16(val);
    }
}

// ---------------------------------------------------------------------------
extern "C" void kernel_launch(void* const* d_in, const int* in_sizes, int n_in,
                              void* d_out, int out_size, void* d_ws, size_t ws_size,
                              hipStream_t stream)
{
    const float* x      = (const float*)d_in[0];
    const float* W_in   = (const float*)d_in[1];
    const float* conv_w = (const float*)d_in[2];
    const float* conv_b = (const float*)d_in[3];
    const float* W_x    = (const float*)d_in[4];
    const float* W_dt   = (const float*)d_in[5];
    const float* b_dt   = (const float*)d_in[6];
    const float* W_out  = (const float*)d_in[7];
    const float* A_log  = (const float*)d_in[8];
    const float* Dp     = (const float*)d_in[9];
    float* out = (float*)d_out;

    // ---- workspace layout (160.5 MB total, with lifetime-checked aliasing) --
    char* ws = (char*)d_ws;
    size_t off = 0;
    auto alloc = [&](size_t bytes) {
        char* p = ws + off;
        off += (bytes + 255) & ~(size_t)255;
        return (void*)p;
    };
    bf16*  xzb   = (bf16*) alloc((size_t)NROWS * 4096 * 2);  // 64 MB; cols 0..2047 reused as U
    bf16*  xc    = (bf16*) alloc((size_t)NROWS * 2048 * 2);  // 32 MB
    bf16*  dtb   = (bf16*) alloc((size_t)NROWS * 2048 * 2);  // 32 MB; first 8 MB aliased by WinT
    float* bdt   = (float*)alloc((size_t)NROWS * 128 * 4);   //  4 MB
    bf16*  WdtT  = (bf16*) alloc((size_t)2048 * 2048 * 2);   //  8 MB
    bf16*  WoutT = (bf16*) alloc((size_t)1024 * 2048 * 2);   //  4 MB
    bf16*  WxT   = (bf16*) alloc((size_t)128 * 2048 * 2);    //  0.5 MB
    char*  scr   = (char*) alloc((size_t)16 << 20);          // 16 MB shared scratch
    // aliases (lifetimes verified):
    bf16*  WinT = (bf16*)dtb;          // used only by GEMM1; dt written later by GEMM3
    bf16*  x_bf = (bf16*)scr;          // used only by GEMM1 (16 MB)
    float* Pb   = (float*)scr;         // written in pass1 (8 MB), after GEMM1
    float* Sb   = (float*)(scr + ((size_t)8 << 20));  // 8 MB
    float* Hb   = Pb;                  // pass2 writes Hinit in-place over P
    bf16*  U    = xzb;                 // pass3 writes U over dead x_inner half

    // ---- weight prep (bf16, transposed to N x K; W_x padded to 128 rows) ---
    transpose_cast<<<dim3(4096/32, 1024/32), dim3(32, 8), 0, stream>>>(W_in,  WinT,  1024, 4096, 4096);
    transpose_cast<<<dim3(2048/32, 2048/32), dim3(32, 8), 0, stream>>>(W_dt,  WdtT,  2048, 2048, 2048);
    transpose_cast<<<dim3(1024/32, 2048/32), dim3(32, 8), 0, stream>>>(W_out, WoutT, 2048, 1024, 1024);
    transpose_cast<<<dim3( 128/32, 2048/32), dim3(32, 8), 0, stream>>>(W_x,   WxT,   2048,   32,  128);
    cast_to_bf16<<<(NROWS * 1024 / 4) / 256, 256, 0, stream>>>(x, x_bf, NROWS * 1024 / 4);

    // xz = x @ W_in  (bf16 out)
    gemm_bt<2><<<dim3(4096/128, NROWS/128), 256, 0, stream>>>(x_bf, 1024, WinT, nullptr, xzb, 4096, nullptr, NROWS, 4096, 1024);
    // xc = silu(causal_conv(x_inner) + b)
    conv_silu<<<(NROWS * 256) / 256, 256, 0, stream>>>(xzb, conv_w, conv_b, xc);
    // bdt = xc @ W_x (padded to 128 cols, fp32 out)
    gemm_bt<0><<<dim3(1, NROWS/128), 256, 0, stream>>>(xc, 2048, WxT, bdt, nullptr, 128, nullptr, NROWS, 128, 2048);
    // dt = softplus(xc @ W_dt + b_dt)  (bf16 out; overwrites WinT region - ok)
    gemm_bt<1><<<dim3(2048/128, NROWS/128), 256, 0, stream>>>(xc, 2048, WdtT, nullptr, dtb, 2048, b_dt, NROWS, 2048, 2048);
    // chunked selective scan
    scan_pass1<<<dim3(DINNER/256, NCHUNK, NBATCH), 256, 0, stream>>>(xc, dtb, bdt, A_log, Pb, Sb);
    scan_pass2<<<(NBATCH * DINNER * 16) / 256, 256, 0, stream>>>(Pb, Sb, Hb);
    scan_pass3<<<dim3(DINNER/256, NCHUNK, NBATCH), 256, 0, stream>>>(xc, dtb, bdt, A_log, Hb, xzb, Dp, U);
    // out = U @ W_out  (U row stride 4096)
    gemm_bt<0><<<dim3(1024/128, NROWS/128), 256, 0, stream>>>(U, 4096, WoutT, out, nullptr, 1024, nullptr, NROWS, 1024, 2048);
}